// Round 7
// baseline (903.280 us; speedup 1.0000x reference)
//
#include <hip/hip_runtime.h>

// ---------------------------------------------------------------------------
// AttentionFusion: 3-modality proj(+LN+ReLU) -> 3-token MHA -> gated fusion
// -> classifier.  B=16384, E=512, H=8, HD=64, NC=6.
// R7: BARRIER-FREE register-resident GEMMs.  R6 profile showed the k-loop
// __syncthreads (vmcnt(0) drain) is the bottleneck (all pipes <20%).  Each
// wave now owns a 64x64 tile, loads A/B fragments global->VGPR directly
// (no LDS), register-double-buffered, zero barriers.  XCD swizzle kept
// (R6: FETCH 314->93 MB).  Gate-before-attention algebra kept.
// Workspace peak 165,806,080 B.
// ---------------------------------------------------------------------------

typedef unsigned short u16;
typedef __bf16 bf16x8 __attribute__((ext_vector_type(8)));
typedef float f32x4  __attribute__((ext_vector_type(4)));
typedef unsigned short u16x8 __attribute__((ext_vector_type(8)));
typedef unsigned short u16x4 __attribute__((ext_vector_type(4)));

#define BATCH 16384

__device__ __forceinline__ u16 f2b(float f) {   // RNE f32->bf16
  union { float f; unsigned int u; } c; c.f = f;
  unsigned int u = c.u;
  return (u16)((u + 0x7fffu + ((u >> 16) & 1u)) >> 16);
}
__device__ __forceinline__ float b2f(u16 h) {
  union { unsigned int u; float f; } c; c.u = ((unsigned int)h) << 16;
  return c.f;
}
__device__ __forceinline__ bf16x8 cvt8(f32x4 lo, f32x4 hi) {
  bf16x8 v;
  #pragma unroll
  for (int d = 0; d < 4; ++d) { v[d] = (__bf16)lo[d]; v[4 + d] = (__bf16)hi[d]; }
  return v;
}

// ---------------------------------------------------------------------------
// fp32 -> bf16 conversion for the 7 GEMM weight matrices (6.4 MB total)
// ---------------------------------------------------------------------------
struct CvtJobs {
  const float* s[7];
  u16* d[7];
  int n4[7];
};

__global__ __launch_bounds__(256) void cvt_w(CvtJobs J) {
  const int stride = gridDim.x * blockDim.x;
  const int tid = blockIdx.x * blockDim.x + threadIdx.x;
  for (int ji = 0; ji < 7; ++ji) {
    const f32x4* __restrict__ s = (const f32x4*)J.s[ji];
    u16x4* __restrict__ d = (u16x4*)J.d[ji];
    const int n4 = J.n4[ji];
    for (int i = tid; i < n4; i += stride) {
      f32x4 v = s[i];
      u16x4 o;
      #pragma unroll
      for (int c = 0; c < 4; ++c) o[c] = f2b(v[c]);
      d[i] = o;
    }
  }
}

// ---------------------------------------------------------------------------
// Barrier-free bf16 GEMM: C(M,N) = A(M,K) @ B(N,K)^T + bias [+ReLU].
// Block = 4 waves in 2x2; each wave owns a 64x64 tile (4x4 of 16x16x32 MFMA),
// loads its fragments global->VGPR (no LDS, no __syncthreads), register
// double-buffered over a 2-step-unrolled k-loop.  Requires K%64==0.
// 1-D grid, XCD-swizzled: the NB N-blocks of one M-block get IDs differing
// by 8 -> same XCD under round-robin -> A served from that XCD's L2.
// ---------------------------------------------------------------------------
template<int EPI>   // 1=bias, 2=bias+relu
__global__ __launch_bounds__(256) void gemm_d(
    const u16* __restrict__ A, const u16* __restrict__ Bw,
    const float* __restrict__ bias, u16* __restrict__ C,
    int K, int ldc, int coff, int NB)
{
  const int id = blockIdx.x;
  const int rr = id & 7, jj = id >> 3;
  const int nb = jj % NB;
  const int mb = rr + ((jj / NB) << 3);
  const int m0 = mb << 7, n0 = nb << 7;

  const int t = threadIdx.x;
  const int wave = t >> 6, lane = t & 63;
  const int wm = wave & 1, wn = wave >> 1;
  const int lr  = lane & 15;
  const int lk8 = (lane >> 4) << 3;

  f32x4 acc[4][4] = {};

  const u16* ap[4];
  const u16* bp[4];
  #pragma unroll
  for (int i = 0; i < 4; ++i) {
    ap[i] = A  + (size_t)(m0 + (wm << 6) + (i << 4) + lr) * K + lk8;
    bp[i] = Bw + (size_t)(n0 + (wn << 6) + (i << 4) + lr) * K + lk8;
  }

  u16x8 a0[4], b0[4], a1[4], b1[4];
  #pragma unroll
  for (int i = 0; i < 4; ++i) { a0[i] = *(const u16x8*)ap[i]; b0[i] = *(const u16x8*)bp[i]; }

  const int nsteps = K >> 5;   // even at every call site (K%64==0)
  for (int s = 0; s < nsteps; s += 2) {
    #pragma unroll
    for (int i = 0; i < 4; ++i) {
      a1[i] = *(const u16x8*)(ap[i] + (s + 1) * 32);
      b1[i] = *(const u16x8*)(bp[i] + (s + 1) * 32);
    }
    #pragma unroll
    for (int mi = 0; mi < 4; ++mi)
      #pragma unroll
      for (int ni = 0; ni < 4; ++ni)
        acc[mi][ni] = __builtin_amdgcn_mfma_f32_16x16x32_bf16(
            __builtin_bit_cast(bf16x8, a0[mi]), __builtin_bit_cast(bf16x8, b0[ni]),
            acc[mi][ni], 0, 0, 0);
    if (s + 2 < nsteps) {
      #pragma unroll
      for (int i = 0; i < 4; ++i) {
        a0[i] = *(const u16x8*)(ap[i] + (s + 2) * 32);
        b0[i] = *(const u16x8*)(bp[i] + (s + 2) * 32);
      }
    }
    #pragma unroll
    for (int mi = 0; mi < 4; ++mi)
      #pragma unroll
      for (int ni = 0; ni < 4; ++ni)
        acc[mi][ni] = __builtin_amdgcn_mfma_f32_16x16x32_bf16(
            __builtin_bit_cast(bf16x8, a1[mi]), __builtin_bit_cast(bf16x8, b1[ni]),
            acc[mi][ni], 0, 0, 0);
  }

  // C/D layout (m89-verified): col = lane&15, row = (lane>>4)*4 + reg
  const int rquad = (lane >> 4) << 2;
  #pragma unroll
  for (int ni = 0; ni < 4; ++ni) {
    const int col = n0 + (wn << 6) + (ni << 4) + lr;
    const float bv = bias[col];
    #pragma unroll
    for (int mi = 0; mi < 4; ++mi) {
      const int rowb = m0 + (wm << 6) + (mi << 4) + rquad;
      #pragma unroll
      for (int r = 0; r < 4; ++r) {
        float v = acc[mi][ni][r] + bv;
        if (EPI == 2) v = fmaxf(v, 0.0f);
        C[(size_t)(rowb + r) * ldc + coff + col] = f2b(v);
      }
    }
  }
}

// ---------------------------------------------------------------------------
// Barrier-free fused 3-modality projection GEMM, fp32 A read directly from
// the inputs (in-register bf16 cvt at MFMA time).  Same wave-owned 64x64
// structure.  Grid 1536, XCD-swizzled (4 N-blocks of one (m,z) share XCD).
// ---------------------------------------------------------------------------
struct P3 {
  const float* A[3];
  const u16* W[3];
  const float* bias[3];
  int K[3];
  int coff[3];
  u16* C;
};

__global__ __launch_bounds__(256) void proj3_k(P3 p) {
  const int id = blockIdx.x;
  const int rr = id & 7, jj = id >> 3;
  const int nb = jj & 3;
  const int mz = rr + ((jj >> 2) << 3);
  const int mb = mz & 127;
  const int z  = mz >> 7;
  const int m0 = mb << 7, n0 = nb << 7;

  const float* __restrict__ A = p.A[z];
  const u16* __restrict__ Bw = p.W[z];
  const int K = p.K[z];

  const int t = threadIdx.x;
  const int wave = t >> 6, lane = t & 63;
  const int wm = wave & 1, wn = wave >> 1;
  const int lr  = lane & 15;
  const int lk8 = (lane >> 4) << 3;

  f32x4 acc[4][4] = {};

  const float* ap[4];
  const u16* bp[4];
  #pragma unroll
  for (int i = 0; i < 4; ++i) {
    ap[i] = A  + (size_t)(m0 + (wm << 6) + (i << 4) + lr) * K + lk8;
    bp[i] = Bw + (size_t)(n0 + (wn << 6) + (i << 4) + lr) * K + lk8;
  }

  f32x4 alo0[4], ahi0[4], alo1[4], ahi1[4];
  u16x8 b0[4], b1[4];
  #pragma unroll
  for (int i = 0; i < 4; ++i) {
    alo0[i] = *(const f32x4*)ap[i];
    ahi0[i] = *(const f32x4*)(ap[i] + 4);
    b0[i]   = *(const u16x8*)bp[i];
  }

  const int nsteps = K >> 5;   // 24 / 20 / 32 — all even
  for (int s = 0; s < nsteps; s += 2) {
    #pragma unroll
    for (int i = 0; i < 4; ++i) {
      const float* q = ap[i] + (s + 1) * 32;
      alo1[i] = *(const f32x4*)q;
      ahi1[i] = *(const f32x4*)(q + 4);
      b1[i]   = *(const u16x8*)(bp[i] + (s + 1) * 32);
    }
    #pragma unroll
    for (int mi = 0; mi < 4; ++mi) {
      const bf16x8 af = cvt8(alo0[mi], ahi0[mi]);
      #pragma unroll
      for (int ni = 0; ni < 4; ++ni)
        acc[mi][ni] = __builtin_amdgcn_mfma_f32_16x16x32_bf16(
            af, __builtin_bit_cast(bf16x8, b0[ni]), acc[mi][ni], 0, 0, 0);
    }
    if (s + 2 < nsteps) {
      #pragma unroll
      for (int i = 0; i < 4; ++i) {
        const float* q = ap[i] + (s + 2) * 32;
        alo0[i] = *(const f32x4*)q;
        ahi0[i] = *(const f32x4*)(q + 4);
        b0[i]   = *(const u16x8*)(bp[i] + (s + 2) * 32);
      }
    }
    #pragma unroll
    for (int mi = 0; mi < 4; ++mi) {
      const bf16x8 af = cvt8(alo1[mi], ahi1[mi]);
      #pragma unroll
      for (int ni = 0; ni < 4; ++ni)
        acc[mi][ni] = __builtin_amdgcn_mfma_f32_16x16x32_bf16(
            af, __builtin_bit_cast(bf16x8, b1[ni]), acc[mi][ni], 0, 0, 0);
    }
  }

  const int rquad = (lane >> 4) << 2;
  #pragma unroll
  for (int ni = 0; ni < 4; ++ni) {
    const int col = n0 + (wn << 6) + (ni << 4) + lr;
    const float bv = p.bias[z][col];
    #pragma unroll
    for (int mi = 0; mi < 4; ++mi) {
      const int rowb = m0 + (wm << 6) + (mi << 4) + rquad;
      #pragma unroll
      for (int r = 0; r < 4; ++r) {
        p.C[(size_t)(rowb + r) * 1536 + p.coff[z] + col] = f2b(acc[mi][ni][r] + bv);
      }
    }
  }
}

// ---------------------------------------------------------------------------
// LN+ReLU over all 3 modality slices of raw (B,1536) bf16 -> rpf (B,1536).
// 384 threads = 6 waves = 2 samples x 3 modalities; one wave per 512-slice.
// ---------------------------------------------------------------------------
__global__ __launch_bounds__(384) void ln3_k(
    const u16* __restrict__ raw, u16* __restrict__ dst,
    const float* __restrict__ g0, const float* __restrict__ b0,
    const float* __restrict__ g1, const float* __restrict__ b1,
    const float* __restrict__ g2, const float* __restrict__ b2)
{
  const int wave = threadIdx.x >> 6, lane = threadIdx.x & 63;
  const int m = wave % 3;
  const int b = blockIdx.x * 2 + wave / 3;
  const size_t off = (size_t)b * 1536 + m * 512 + lane * 8;
  u16x8 xa = *(const u16x8*)&raw[off];
  float x[8];
  float sum = 0.f, sq = 0.f;
  #pragma unroll
  for (int d = 0; d < 8; ++d) { float f = b2f(xa[d]); x[d] = f; sum += f; sq += f * f; }
  #pragma unroll
  for (int o = 32; o > 0; o >>= 1) { sum += __shfl_xor(sum, o); sq += __shfl_xor(sq, o); }
  const float mean = sum * (1.0f / 512.0f);
  const float var = sq * (1.0f / 512.0f) - mean * mean;
  const float rs = rsqrtf(var + 1e-5f);
  const float* g = (m == 0) ? g0 : (m == 1) ? g1 : g2;
  const float* bb = (m == 0) ? b0 : (m == 1) ? b1 : b2;
  u16x8 o;
  #pragma unroll
  for (int d = 0; d < 8; ++d) {
    float y = (x[d] - mean) * rs * g[lane * 8 + d] + bb[lane * 8 + d];
    o[d] = f2b(fmaxf(y, 0.0f));
  }
  *(u16x8*)&dst[off] = o;
}

// ---------------------------------------------------------------------------
// Row LayerNorm + ReLU, bf16 in -> bf16 out. One wave per row, 4 rows/block.
// ---------------------------------------------------------------------------
template<int E>
__global__ __launch_bounds__(256) void ln_relu_k(
    const u16* __restrict__ src, u16* __restrict__ dst,
    const float* __restrict__ gg, const float* __restrict__ bb)
{
  constexpr int V = E >> 6;
  const int wave = threadIdx.x >> 6, lane = threadIdx.x & 63;
  const int row = blockIdx.x * 4 + wave;
  const u16* s = src + (size_t)row * E + lane * V;
  float x[V];
  float sum = 0.f, sq = 0.f;
  #pragma unroll
  for (int i = 0; i < V; i += 4) {
    u16x4 v = *(const u16x4*)(s + i);
    #pragma unroll
    for (int c = 0; c < 4; ++c) { float f = b2f(v[c]); x[i + c] = f; sum += f; sq += f * f; }
  }
  #pragma unroll
  for (int off = 32; off > 0; off >>= 1) {
    sum += __shfl_xor(sum, off);
    sq  += __shfl_xor(sq,  off);
  }
  const float invE = 1.0f / (float)E;
  const float m = sum * invE;
  const float var = sq * invE - m * m;
  const float rs = rsqrtf(var + 1e-5f);
  u16* d = dst + (size_t)row * E + lane * V;
  const float* g = gg + lane * V;
  const float* b = bb + lane * V;
  #pragma unroll
  for (int i = 0; i < V; i += 4) {
    u16x4 o;
    #pragma unroll
    for (int c = 0; c < 4; ++c) {
      float y = (x[i + c] - m) * rs * g[i + c] + b[i + c];
      o[c] = f2b(fmaxf(y, 0.0f));
    }
    *(u16x4*)(d + i) = o;
  }
}

// ---------------------------------------------------------------------------
// gate2: (512->3) + softmax.  One wave per sample; writes gate_out (B,3) fp32.
// ---------------------------------------------------------------------------
__global__ __launch_bounds__(256) void gate2_k(
    const u16* __restrict__ gateh, const float* __restrict__ gw2,
    const float* __restrict__ gb2, float* __restrict__ gate_out)
{
  const int wave = threadIdx.x >> 6, lane = threadIdx.x & 63;
  const int b = blockIdx.x * 4 + wave;
  float x[8];
  u16x8 xa = *(const u16x8*)&gateh[(size_t)b * 512 + lane * 8];
  #pragma unroll
  for (int d = 0; d < 8; ++d) x[d] = b2f(xa[d]);
  float s[3] = {0.f, 0.f, 0.f};
  #pragma unroll
  for (int j = 0; j < 3; ++j) {
    const float* w = gw2 + j * 512 + lane * 8;
    #pragma unroll
    for (int d = 0; d < 8; ++d) s[j] += x[d] * w[d];
  }
  #pragma unroll
  for (int m = 1; m < 64; m <<= 1)
    #pragma unroll
    for (int j = 0; j < 3; ++j) s[j] += __shfl_xor(s[j], m);
  if (lane == 0) {
    #pragma unroll
    for (int j = 0; j < 3; ++j) s[j] += gb2[j];
    const float mx = fmaxf(s[0], fmaxf(s[1], s[2]));
    float e0 = __expf(s[0] - mx), e1 = __expf(s[1] - mx), e2 = __expf(s[2] - mx);
    const float inv = 1.0f / (e0 + e1 + e2);
    gate_out[b * 3 + 0] = e0 * inv;
    gate_out[b * 3 + 1] = e1 * inv;
    gate_out[b * 3 + 2] = e2 * inv;
  }
}

// ---------------------------------------------------------------------------
// 3-token 8-head attention + gate application for a chunk of NB samples.
// qkv: (3*NB,1536) bf16 [q|k|v]; emits the GATED context sum directly:
// ctxg[b0+b] = sum_i gate_i * ctx_i   (exact: out-proj is linear, sum g = 1).
// 8 lanes per (b,h), each lane owns 8 of the 64 head dims.
// ---------------------------------------------------------------------------
__global__ __launch_bounds__(256) void attn_gate_k(
    const u16* __restrict__ qkv, const float* __restrict__ gate,
    u16* __restrict__ ctxg, int b0)
{
  const int gid = blockIdx.x * 256 + threadIdx.x;
  const int b = gid >> 6;
  const int h = (threadIdx.x >> 3) & 7;
  const int ld = threadIdx.x & 7;
  const size_t rb = (size_t)(3 * b) * 1536 + h * 64 + ld * 8;

  float q[3][8], k[3][8], v[3][8];
  #pragma unroll
  for (int i = 0; i < 3; ++i) {
    u16x8 qa = *(const u16x8*)&qkv[rb + (size_t)i * 1536];
    u16x8 ka = *(const u16x8*)&qkv[rb + (size_t)i * 1536 + 512];
    u16x8 va = *(const u16x8*)&qkv[rb + (size_t)i * 1536 + 1024];
    #pragma unroll
    for (int d = 0; d < 8; ++d) { q[i][d] = b2f(qa[d]); k[i][d] = b2f(ka[d]); v[i][d] = b2f(va[d]); }
  }
  float s[9];
  #pragma unroll
  for (int i = 0; i < 3; ++i)
    #pragma unroll
    for (int j = 0; j < 3; ++j) {
      float a = 0.f;
      #pragma unroll
      for (int d = 0; d < 8; ++d) a += q[i][d] * k[j][d];
      s[i * 3 + j] = a;
    }
  #pragma unroll
  for (int m = 1; m < 8; m <<= 1)
    #pragma unroll
    for (int e = 0; e < 9; ++e) s[e] += __shfl_xor(s[e], m);

  const float g0 = gate[(size_t)(b0 + b) * 3 + 0];
  const float g1 = gate[(size_t)(b0 + b) * 3 + 1];
  const float g2 = gate[(size_t)(b0 + b) * 3 + 2];
  const float gg[3] = {g0, g1, g2};

  float o[8] = {};
  const float sc = 0.125f;  // 1/sqrt(64)
  #pragma unroll
  for (int i = 0; i < 3; ++i) {
    const float a0 = s[i * 3 + 0] * sc, a1 = s[i * 3 + 1] * sc, a2 = s[i * 3 + 2] * sc;
    const float mx = fmaxf(a0, fmaxf(a1, a2));
    float e0 = __expf(a0 - mx), e1 = __expf(a1 - mx), e2 = __expf(a2 - mx);
    const float inv = gg[i] / (e0 + e1 + e2);
    e0 *= inv; e1 *= inv; e2 *= inv;
    #pragma unroll
    for (int d = 0; d < 8; ++d)
      o[d] += e0 * v[0][d] + e1 * v[1][d] + e2 * v[2][d];
  }
  u16x8 ov;
  #pragma unroll
  for (int d = 0; d < 8; ++d) ov[d] = f2b(o[d]);
  *(u16x8*)&ctxg[(size_t)(b0 + b) * 512 + h * 64 + ld * 8] = ov;
}

// ---------------------------------------------------------------------------
// classifier tail: logits = h(256) @ cw2(6,256)^T + cb2.  One wave per b.
// ---------------------------------------------------------------------------
__global__ __launch_bounds__(256) void cls2_k(
    const u16* __restrict__ hh, const float* __restrict__ cw2,
    const float* __restrict__ cb2, float* __restrict__ logits)
{
  const int wave = threadIdx.x >> 6, lane = threadIdx.x & 63;
  const int b = blockIdx.x * 4 + wave;
  float x[4];
  u16x4 xa = *(const u16x4*)&hh[(size_t)b * 256 + lane * 4];
  #pragma unroll
  for (int d = 0; d < 4; ++d) x[d] = b2f(xa[d]);
  float s[6] = {};
  #pragma unroll
  for (int j = 0; j < 6; ++j) {
    const float* w = cw2 + j * 256 + lane * 4;
    #pragma unroll
    for (int d = 0; d < 4; ++d) s[j] += x[d] * w[d];
  }
  #pragma unroll
  for (int m = 1; m < 64; m <<= 1)
    #pragma unroll
    for (int j = 0; j < 6; ++j) s[j] += __shfl_xor(s[j], m);
  if (lane < 6) logits[(size_t)b * 6 + lane] = s[lane] + cb2[lane];
}

// ---------------------------------------------------------------------------
extern "C" void kernel_launch(void* const* d_in, const int* in_sizes, int n_in,
                              void* d_out, int out_size, void* d_ws, size_t ws_size,
                              hipStream_t stream) {
  const float* rgb       = (const float*)d_in[0];
  const float* pose      = (const float*)d_in[1];
  const float* flow      = (const float*)d_in[2];
  const float* rgb_w     = (const float*)d_in[3];
  const float* rgb_b     = (const float*)d_in[4];
  const float* rgb_g     = (const float*)d_in[5];
  const float* rgb_beta  = (const float*)d_in[6];
  const float* pose_w    = (const float*)d_in[7];
  const float* pose_b    = (const float*)d_in[8];
  const float* pose_g    = (const float*)d_in[9];
  const float* pose_beta = (const float*)d_in[10];
  const float* flow_w    = (const float*)d_in[11];
  const float* flow_b    = (const float*)d_in[12];
  const float* flow_g    = (const float*)d_in[13];
  const float* flow_beta = (const float*)d_in[14];
  const float* in_w      = (const float*)d_in[15];
  const float* in_b      = (const float*)d_in[16];
  const float* out_w     = (const float*)d_in[17];
  const float* out_b     = (const float*)d_in[18];
  const float* gw1       = (const float*)d_in[19];
  const float* gb1       = (const float*)d_in[20];
  const float* gw2       = (const float*)d_in[21];
  const float* gb2       = (const float*)d_in[22];
  const float* cw1       = (const float*)d_in[23];
  const float* cb1       = (const float*)d_in[24];
  const float* cg        = (const float*)d_in[25];
  const float* cbeta     = (const float*)d_in[26];
  const float* cw2       = (const float*)d_in[27];
  const float* cb2       = (const float*)d_in[28];

  float* logits_out = (float*)d_out;                      // (16384, 6)
  float* gate_out   = (float*)d_out + (size_t)BATCH * 6;  // (16384, 3)

  // ---- static workspace layout, peak 165,806,080 B -------------------------
  char* ws = (char*)d_ws;
  u16* w_rgb  = (u16*)(ws + 0);
  u16* w_pose = (u16*)(ws + 786432);
  u16* w_flow = (u16*)(ws + 1441792);
  u16* w_in   = (u16*)(ws + 2490368);
  u16* w_out  = (u16*)(ws + 4063232);
  u16* w_g1   = (u16*)(ws + 4587520);
  u16* w_c1   = (u16*)(ws + 6160384);
  char* rpfB = ws + 6422528;
  char* B2   = ws + 56754176;
  char* Cb   = ws + 132251648;
  char* Db   = ws + 149028864;

  u16*   rpf      = (u16*)rpfB;     // (B,1536) bf16 — also the (3B,512) view
  u16*   raw      = (u16*)B2;       // (B,1536) bf16 pre-LN proj outputs
  u16*   qkv_buf  = (u16*)B2;       // (24576,1536) bf16 chunk (raw dead)
  u16*   gateh    = (u16*)Cb;       // (B,512) bf16
  u16*   fusedb   = (u16*)Cb;       // overlay (gateh dead after gate2)
  u16*   ctxg     = (u16*)Db;       // (B,512) bf16 gated context
  u16*   cls_tmp  = (u16*)Db;       // (B,256) bf16 overlay (ctxg dead)
  u16*   h_bf     = (u16*)(Db + 8388608);

  // ---- 1. convert GEMM weights to bf16 (6.4 MB) ----------------------------
  CvtJobs J;
  const float* srcs[7] = {rgb_w, pose_w, flow_w, in_w, out_w, gw1, cw1};
  u16* dsts[7] = {w_rgb, w_pose, w_flow, w_in, w_out, w_g1, w_c1};
  int ns[7] = {512 * 768, 512 * 640, 512 * 1024, 1536 * 512, 512 * 512, 512 * 1536, 256 * 512};
  for (int i = 0; i < 7; ++i) { J.s[i] = srcs[i]; J.d[i] = dsts[i]; J.n4[i] = ns[i] / 4; }
  cvt_w<<<128, 256, 0, stream>>>(J);

  dim3 blk(256);
  // ---- 2. fused 3-proj GEMM (fp32 A direct, barrier-free) -> raw; ln3 ------
  P3 p;
  p.A[0] = rgb;  p.W[0] = w_rgb;  p.bias[0] = rgb_b;  p.K[0] = 768;  p.coff[0] = 0;
  p.A[1] = pose; p.W[1] = w_pose; p.bias[1] = pose_b; p.K[1] = 640;  p.coff[1] = 512;
  p.A[2] = flow; p.W[2] = w_flow; p.bias[2] = flow_b; p.K[2] = 1024; p.coff[2] = 1024;
  p.C = raw;
  proj3_k<<<1536, blk, 0, stream>>>(p);
  ln3_k<<<BATCH / 2, dim3(384), 0, stream>>>(raw, rpf, rgb_g, rgb_beta, pose_g, pose_beta, flow_g, flow_beta);

  // ---- 3. gate MLP (needs only rpf): gate1 GEMM + gate2 softmax ------------
  gemm_d<2><<<4 * (BATCH / 128), blk, 0, stream>>>(rpf, w_g1, gb1, gateh, 1536, 512, 0, 4);
  gate2_k<<<BATCH / 4, blk, 0, stream>>>(gateh, gw2, gb2, gate_out);

  // ---- 4. qkv GEMM + gated attention, 2 chunks of 8192 samples -------------
  for (int c = 0; c < 2; ++c) {
    const u16* a_chunk = rpf + (size_t)c * 8192 * 1536;   // (24576,512) view
    gemm_d<1><<<12 * (3 * 8192 / 128), blk, 0, stream>>>(
        a_chunk, w_in, in_b, qkv_buf, 512, 1536, 0, 12);
    attn_gate_k<<<8192 / 4, blk, 0, stream>>>(qkv_buf, gate_out, ctxg, c * 8192);
  }

  // ---- 5. out-proj on the GATED sum (B x 512 -> 512) -----------------------
  gemm_d<1><<<4 * (BATCH / 128), blk, 0, stream>>>(ctxg, w_out, out_b, fusedb, 512, 512, 0, 4);

  // ---- 6. classifier: GEMM -> LN+ReLU -> logits ----------------------------
  gemm_d<1><<<2 * (BATCH / 128), blk, 0, stream>>>(fusedb, w_c1, cb1, cls_tmp, 512, 256, 0, 2);
  ln_relu_k<256><<<BATCH / 4, blk, 0, stream>>>(cls_tmp, h_bf, cg, cbeta);
  cls2_k<<<BATCH / 4, blk, 0, stream>>>(h_bf, cw2, cb2, logits_out);

  (void)in_sizes; (void)n_in; (void)out_size; (void)ws_size;
}

// Round 8
// 612.077 us; speedup vs baseline: 1.4758x; 1.4758x over previous
//
#include <hip/hip_runtime.h>

// ---------------------------------------------------------------------------
// AttentionFusion: 3-modality proj(+LN+ReLU) -> 3-token MHA -> gated fusion
// -> classifier.  B=16384, E=512, H=8, HD=64, NC=6.
// R8: wave-autonomous GEMM — 1 wave (64 threads) per block owning a 64x64
// tile, private double-buffered LDS staged via global_load_lds, ZERO
// __syncthreads (per-wave vmcnt/lgkmcnt only; ~10 independent blocks/CU).
// R7's register-gather mistake reverted: LDS staging keeps coalesced 16B/lane
// loads.  Inputs pre-converted to bf16 (one cvt pass) so ALL GEMMs share one
// kernel.  XCD swizzle kept (R6: FETCH 314->93 MB).  Gate-before-attention
// algebra kept.  Workspace = R4's exact 186,777,600 B plan (ran clean).
// ---------------------------------------------------------------------------

typedef unsigned short u16;
typedef __bf16 bf16x8 __attribute__((ext_vector_type(8)));
typedef float f32x4  __attribute__((ext_vector_type(4)));
typedef unsigned short u16x8 __attribute__((ext_vector_type(8)));
typedef unsigned short u16x4 __attribute__((ext_vector_type(4)));

#define BATCH 16384

__device__ __forceinline__ u16 f2b(float f) {   // RNE f32->bf16
  union { float f; unsigned int u; } c; c.f = f;
  unsigned int u = c.u;
  return (u16)((u + 0x7fffu + ((u >> 16) & 1u)) >> 16);
}
__device__ __forceinline__ float b2f(u16 h) {
  union { unsigned int u; float f; } c; c.u = ((unsigned int)h) << 16;
  return c.f;
}

// ---------------------------------------------------------------------------
// fp32 -> bf16 conversion: 3 inputs + 7 weight matrices
// ---------------------------------------------------------------------------
struct CvtJobs {
  const float* s[10];
  u16* d[10];
  int n4[10];
};

__global__ __launch_bounds__(256) void cvt_multi(CvtJobs J) {
  const int stride = gridDim.x * blockDim.x;
  const int tid = blockIdx.x * blockDim.x + threadIdx.x;
  for (int ji = 0; ji < 10; ++ji) {
    const f32x4* __restrict__ s = (const f32x4*)J.s[ji];
    u16x4* __restrict__ d = (u16x4*)J.d[ji];
    const int n4 = J.n4[ji];
    for (int i = tid; i < n4; i += stride) {
      f32x4 v = s[i];
      u16x4 o;
      #pragma unroll
      for (int c = 0; c < 4; ++c) o[c] = f2b(v[c]);
      d[i] = o;
    }
  }
}

// ---------------------------------------------------------------------------
// Wave-autonomous bf16 GEMM: C(M,N) = A(M,K) @ B(N,K)^T + bias [+ReLU].
// One wave per block, 64x64 tile (4x4 of 16x16x32 MFMA), BK=32.
// Private LDS double buffer (A 4KB + B 4KB per buf = 16KB), staged via
// global_load_lds (4 issues of 1KB each per tile).  NO __syncthreads —
// the staging wave is the consuming wave; only its own vmcnt/lgkmcnt waits.
// Loop order: read frags(cur) -> issue stage(next) -> MFMA, so each prefetch
// flies during the MFMA phase and the vmcnt wait at the next read covers
// already-old loads.  1-D grid, XCD-swizzled (NB N-tiles of one M-tile get
// IDs differing by 8 -> same XCD).  Requires M%64==0 (Mtiles%8==0), N%64==0,
// K%32==0.
// ---------------------------------------------------------------------------
template<int EPI>   // 1=bias, 2=bias+relu
__global__ __launch_bounds__(64, 4) void gemm_w(
    const u16* __restrict__ A, const u16* __restrict__ Bw,
    const float* __restrict__ bias, u16* __restrict__ C,
    int K, int ldc, int coff, int NB)
{
  __shared__ __align__(16) u16 As[2][2048];   // 64 rows x 32 bf16
  __shared__ __align__(16) u16 Bs[2][2048];
  const int id = blockIdx.x;
  const int rr = id & 7, jj = id >> 3;
  const int nb = jj % NB;
  const int mb = rr + ((jj / NB) << 3);
  const int m0 = mb << 6, n0 = nb << 6;

  const int lane = threadIdx.x;        // 0..63
  const int lr  = lane & 15;
  const int lk8 = (lane >> 4) << 3;
  const int srow = lane >> 2;          // 0..15 (16 rows per staging issue)
  const int scol = (lane & 3) << 4;    // byte col within 64B row

  f32x4 acc[4][4] = {};

  const size_t rowB = (size_t)K * 2;
  const char* Ab = (const char*)A + (size_t)m0 * rowB + scol;
  const char* Bb = (const char*)Bw + (size_t)n0 * rowB + scol;

  auto stage = [&](int s, int buf) {
    const char* Ak = Ab + (size_t)s * 64;
    const char* Bk = Bb + (size_t)s * 64;
    #pragma unroll
    for (int j = 0; j < 4; ++j) {
      __builtin_amdgcn_global_load_lds(
          (const __attribute__((address_space(1))) void*)(Ak + (size_t)(j * 16 + srow) * rowB),
          (__attribute__((address_space(3))) void*)((char*)As[buf] + (j << 10)),
          16, 0, 0);
      __builtin_amdgcn_global_load_lds(
          (const __attribute__((address_space(1))) void*)(Bk + (size_t)(j * 16 + srow) * rowB),
          (__attribute__((address_space(3))) void*)((char*)Bs[buf] + (j << 10)),
          16, 0, 0);
    }
  };

  const int nsteps = K >> 5;
  stage(0, 0);
  for (int s = 0; s < nsteps; ++s) {
    const int cur = s & 1;
    // read this step's fragments (waits on the loads issued last iteration)
    bf16x8 af[4], bfr[4];
    #pragma unroll
    for (int i = 0; i < 4; ++i) {
      af[i]  = __builtin_bit_cast(bf16x8, *(const u16x8*)&As[cur][(i * 16 + lr) * 32 + lk8]);
      bfr[i] = __builtin_bit_cast(bf16x8, *(const u16x8*)&Bs[cur][(i * 16 + lr) * 32 + lk8]);
    }
    // prefetch next tile into the other buffer — flies during the MFMAs
    if (s + 1 < nsteps) stage(s + 1, cur ^ 1);
    #pragma unroll
    for (int mi = 0; mi < 4; ++mi)
      #pragma unroll
      for (int ni = 0; ni < 4; ++ni)
        acc[mi][ni] = __builtin_amdgcn_mfma_f32_16x16x32_bf16(
            af[mi], bfr[ni], acc[mi][ni], 0, 0, 0);
  }

  // C/D layout (m89-verified): col = lane&15, row = (lane>>4)*4 + reg
  const int rquad = (lane >> 4) << 2;
  #pragma unroll
  for (int ni = 0; ni < 4; ++ni) {
    const int col = n0 + (ni << 4) + lr;
    const float bv = bias[col];
    #pragma unroll
    for (int mi = 0; mi < 4; ++mi) {
      const int rowb = m0 + (mi << 4) + rquad;
      #pragma unroll
      for (int r = 0; r < 4; ++r) {
        float v = acc[mi][ni][r] + bv;
        if (EPI == 2) v = fmaxf(v, 0.0f);
        C[(size_t)(rowb + r) * ldc + coff + col] = f2b(v);
      }
    }
  }
}

// ---------------------------------------------------------------------------
// LN+ReLU over all 3 modality slices of raw (B,1536) bf16 -> rpf (B,1536).
// 384 threads = 6 waves = 2 samples x 3 modalities; one wave per 512-slice.
// ---------------------------------------------------------------------------
__global__ __launch_bounds__(384) void ln3_k(
    const u16* __restrict__ raw, u16* __restrict__ dst,
    const float* __restrict__ g0, const float* __restrict__ b0,
    const float* __restrict__ g1, const float* __restrict__ b1,
    const float* __restrict__ g2, const float* __restrict__ b2)
{
  const int wave = threadIdx.x >> 6, lane = threadIdx.x & 63;
  const int m = wave % 3;
  const int b = blockIdx.x * 2 + wave / 3;
  const size_t off = (size_t)b * 1536 + m * 512 + lane * 8;
  u16x8 xa = *(const u16x8*)&raw[off];
  float x[8];
  float sum = 0.f, sq = 0.f;
  #pragma unroll
  for (int d = 0; d < 8; ++d) { float f = b2f(xa[d]); x[d] = f; sum += f; sq += f * f; }
  #pragma unroll
  for (int o = 32; o > 0; o >>= 1) { sum += __shfl_xor(sum, o); sq += __shfl_xor(sq, o); }
  const float mean = sum * (1.0f / 512.0f);
  const float var = sq * (1.0f / 512.0f) - mean * mean;
  const float rs = rsqrtf(var + 1e-5f);
  const float* g = (m == 0) ? g0 : (m == 1) ? g1 : g2;
  const float* bb = (m == 0) ? b0 : (m == 1) ? b1 : b2;
  u16x8 o;
  #pragma unroll
  for (int d = 0; d < 8; ++d) {
    float y = (x[d] - mean) * rs * g[lane * 8 + d] + bb[lane * 8 + d];
    o[d] = f2b(fmaxf(y, 0.0f));
  }
  *(u16x8*)&dst[off] = o;
}

// ---------------------------------------------------------------------------
// Row LayerNorm + ReLU, bf16 in -> bf16 out. One wave per row, 4 rows/block.
// ---------------------------------------------------------------------------
template<int E>
__global__ __launch_bounds__(256) void ln_relu_k(
    const u16* __restrict__ src, u16* __restrict__ dst,
    const float* __restrict__ gg, const float* __restrict__ bb)
{
  constexpr int V = E >> 6;
  const int wave = threadIdx.x >> 6, lane = threadIdx.x & 63;
  const int row = blockIdx.x * 4 + wave;
  const u16* s = src + (size_t)row * E + lane * V;
  float x[V];
  float sum = 0.f, sq = 0.f;
  #pragma unroll
  for (int i = 0; i < V; i += 4) {
    u16x4 v = *(const u16x4*)(s + i);
    #pragma unroll
    for (int c = 0; c < 4; ++c) { float f = b2f(v[c]); x[i + c] = f; sum += f; sq += f * f; }
  }
  #pragma unroll
  for (int off = 32; off > 0; off >>= 1) {
    sum += __shfl_xor(sum, off);
    sq  += __shfl_xor(sq,  off);
  }
  const float invE = 1.0f / (float)E;
  const float m = sum * invE;
  const float var = sq * invE - m * m;
  const float rs = rsqrtf(var + 1e-5f);
  u16* d = dst + (size_t)row * E + lane * V;
  const float* g = gg + lane * V;
  const float* b = bb + lane * V;
  #pragma unroll
  for (int i = 0; i < V; i += 4) {
    u16x4 o;
    #pragma unroll
    for (int c = 0; c < 4; ++c) {
      float y = (x[i + c] - m) * rs * g[i + c] + b[i + c];
      o[c] = f2b(fmaxf(y, 0.0f));
    }
    *(u16x4*)(d + i) = o;
  }
}

// ---------------------------------------------------------------------------
// gate2: (512->3) + softmax.  One wave per sample; writes gate_out (B,3) fp32.
// ---------------------------------------------------------------------------
__global__ __launch_bounds__(256) void gate2_k(
    const u16* __restrict__ gateh, const float* __restrict__ gw2,
    const float* __restrict__ gb2, float* __restrict__ gate_out)
{
  const int wave = threadIdx.x >> 6, lane = threadIdx.x & 63;
  const int b = blockIdx.x * 4 + wave;
  float x[8];
  u16x8 xa = *(const u16x8*)&gateh[(size_t)b * 512 + lane * 8];
  #pragma unroll
  for (int d = 0; d < 8; ++d) x[d] = b2f(xa[d]);
  float s[3] = {0.f, 0.f, 0.f};
  #pragma unroll
  for (int j = 0; j < 3; ++j) {
    const float* w = gw2 + j * 512 + lane * 8;
    #pragma unroll
    for (int d = 0; d < 8; ++d) s[j] += x[d] * w[d];
  }
  #pragma unroll
  for (int m = 1; m < 64; m <<= 1)
    #pragma unroll
    for (int j = 0; j < 3; ++j) s[j] += __shfl_xor(s[j], m);
  if (lane == 0) {
    #pragma unroll
    for (int j = 0; j < 3; ++j) s[j] += gb2[j];
    const float mx = fmaxf(s[0], fmaxf(s[1], s[2]));
    float e0 = __expf(s[0] - mx), e1 = __expf(s[1] - mx), e2 = __expf(s[2] - mx);
    const float inv = 1.0f / (e0 + e1 + e2);
    gate_out[b * 3 + 0] = e0 * inv;
    gate_out[b * 3 + 1] = e1 * inv;
    gate_out[b * 3 + 2] = e2 * inv;
  }
}

// ---------------------------------------------------------------------------
// 3-token 8-head attention + gate application for a chunk of NB samples.
// qkv: (3*NB,1536) bf16 [q|k|v]; emits the GATED context sum directly:
// ctxg[b0+b] = sum_i gate_i * ctx_i   (exact: out-proj is linear, sum g = 1).
// 8 lanes per (b,h), each lane owns 8 of the 64 head dims.
// ---------------------------------------------------------------------------
__global__ __launch_bounds__(256) void attn_gate_k(
    const u16* __restrict__ qkv, const float* __restrict__ gate,
    u16* __restrict__ ctxg, int b0)
{
  const int gid = blockIdx.x * 256 + threadIdx.x;
  const int b = gid >> 6;
  const int h = (threadIdx.x >> 3) & 7;
  const int ld = threadIdx.x & 7;
  const size_t rb = (size_t)(3 * b) * 1536 + h * 64 + ld * 8;

  float q[3][8], k[3][8], v[3][8];
  #pragma unroll
  for (int i = 0; i < 3; ++i) {
    u16x8 qa = *(const u16x8*)&qkv[rb + (size_t)i * 1536];
    u16x8 ka = *(const u16x8*)&qkv[rb + (size_t)i * 1536 + 512];
    u16x8 va = *(const u16x8*)&qkv[rb + (size_t)i * 1536 + 1024];
    #pragma unroll
    for (int d = 0; d < 8; ++d) { q[i][d] = b2f(qa[d]); k[i][d] = b2f(ka[d]); v[i][d] = b2f(va[d]); }
  }
  float s[9];
  #pragma unroll
  for (int i = 0; i < 3; ++i)
    #pragma unroll
    for (int j = 0; j < 3; ++j) {
      float a = 0.f;
      #pragma unroll
      for (int d = 0; d < 8; ++d) a += q[i][d] * k[j][d];
      s[i * 3 + j] = a;
    }
  #pragma unroll
  for (int m = 1; m < 8; m <<= 1)
    #pragma unroll
    for (int e = 0; e < 9; ++e) s[e] += __shfl_xor(s[e], m);

  const float g0 = gate[(size_t)(b0 + b) * 3 + 0];
  const float g1 = gate[(size_t)(b0 + b) * 3 + 1];
  const float g2 = gate[(size_t)(b0 + b) * 3 + 2];
  const float gg[3] = {g0, g1, g2};

  float o[8] = {};
  const float sc = 0.125f;  // 1/sqrt(64)
  #pragma unroll
  for (int i = 0; i < 3; ++i) {
    const float a0 = s[i * 3 + 0] * sc, a1 = s[i * 3 + 1] * sc, a2 = s[i * 3 + 2] * sc;
    const float mx = fmaxf(a0, fmaxf(a1, a2));
    float e0 = __expf(a0 - mx), e1 = __expf(a1 - mx), e2 = __expf(a2 - mx);
    const float inv = gg[i] / (e0 + e1 + e2);
    e0 *= inv; e1 *= inv; e2 *= inv;
    #pragma unroll
    for (int d = 0; d < 8; ++d)
      o[d] += e0 * v[0][d] + e1 * v[1][d] + e2 * v[2][d];
  }
  u16x8 ov;
  #pragma unroll
  for (int d = 0; d < 8; ++d) ov[d] = f2b(o[d]);
  *(u16x8*)&ctxg[(size_t)(b0 + b) * 512 + h * 64 + ld * 8] = ov;
}

// ---------------------------------------------------------------------------
// classifier tail: logits = h(256) @ cw2(6,256)^T + cb2.  One wave per b.
// ---------------------------------------------------------------------------
__global__ __launch_bounds__(256) void cls2_k(
    const u16* __restrict__ hh, const float* __restrict__ cw2,
    const float* __restrict__ cb2, float* __restrict__ logits)
{
  const int wave = threadIdx.x >> 6, lane = threadIdx.x & 63;
  const int b = blockIdx.x * 4 + wave;
  float x[4];
  u16x4 xa = *(const u16x4*)&hh[(size_t)b * 256 + lane * 4];
  #pragma unroll
  for (int d = 0; d < 4; ++d) x[d] = b2f(xa[d]);
  float s[6] = {};
  #pragma unroll
  for (int j = 0; j < 6; ++j) {
    const float* w = cw2 + j * 256 + lane * 4;
    #pragma unroll
    for (int d = 0; d < 4; ++d) s[j] += x[d] * w[d];
  }
  #pragma unroll
  for (int m = 1; m < 64; m <<= 1)
    #pragma unroll
    for (int j = 0; j < 6; ++j) s[j] += __shfl_xor(s[j], m);
  if (lane < 6) logits[(size_t)b * 6 + lane] = s[lane] + cb2[lane];
}

// ---------------------------------------------------------------------------
extern "C" void kernel_launch(void* const* d_in, const int* in_sizes, int n_in,
                              void* d_out, int out_size, void* d_ws, size_t ws_size,
                              hipStream_t stream) {
  const float* rgb       = (const float*)d_in[0];
  const float* pose      = (const float*)d_in[1];
  const float* flow      = (const float*)d_in[2];
  const float* rgb_w     = (const float*)d_in[3];
  const float* rgb_b     = (const float*)d_in[4];
  const float* rgb_g     = (const float*)d_in[5];
  const float* rgb_beta  = (const float*)d_in[6];
  const float* pose_w    = (const float*)d_in[7];
  const float* pose_b    = (const float*)d_in[8];
  const float* pose_g    = (const float*)d_in[9];
  const float* pose_beta = (const float*)d_in[10];
  const float* flow_w    = (const float*)d_in[11];
  const float* flow_b    = (const float*)d_in[12];
  const float* flow_g    = (const float*)d_in[13];
  const float* flow_beta = (const float*)d_in[14];
  const float* in_w      = (const float*)d_in[15];
  const float* in_b      = (const float*)d_in[16];
  const float* out_w     = (const float*)d_in[17];
  const float* out_b     = (const float*)d_in[18];
  const float* gw1       = (const float*)d_in[19];
  const float* gb1       = (const float*)d_in[20];
  const float* gw2       = (const float*)d_in[21];
  const float* gb2       = (const float*)d_in[22];
  const float* cw1       = (const float*)d_in[23];
  const float* cb1       = (const float*)d_in[24];
  const float* cg        = (const float*)d_in[25];
  const float* cbeta     = (const float*)d_in[26];
  const float* cw2       = (const float*)d_in[27];
  const float* cb2       = (const float*)d_in[28];

  float* logits_out = (float*)d_out;                      // (16384, 6)
  float* gate_out   = (float*)d_out + (size_t)BATCH * 6;  // (16384, 3)

  // ---- static workspace layout, peak 186,777,600 B (= R4's, ran clean) -----
  // [0, 6.42M)          : 7 weight matrices, bf16
  // rpf   [6.42M)       : (B,1536) bf16 — live until last qkv chunk
  // raw   [56.75M)      : (B,1536) pre-LN; gateh overlays; qkv_buf overlays
  // qkv   [56.75,132.25M): (24576,1536) chunk (over raw + dead rgb_bf)
  // inputs[107.09M)     : rgb/pose/flow bf16 (79.7M, dead after proj)
  // ctxg  [132.25M)     : (B,512) — over dead pose_bf
  // fusedb[149.03M)     : (B,512) — over dead flow_bf
  // cls_tmp/h_bf [165.8M): (B,256) x2
  char* ws = (char*)d_ws;
  u16* w_rgb  = (u16*)(ws + 0);
  u16* w_pose = (u16*)(ws + 786432);
  u16* w_flow = (u16*)(ws + 1441792);
  u16* w_in   = (u16*)(ws + 2490368);
  u16* w_out  = (u16*)(ws + 4063232);
  u16* w_g1   = (u16*)(ws + 4587520);
  u16* w_c1   = (u16*)(ws + 6160384);
  u16* rpf     = (u16*)(ws + 6422528);
  u16* raw     = (u16*)(ws + 56754176);
  u16* gateh   = (u16*)(ws + 56754176);    // over dead raw
  u16* qkv_buf = (u16*)(ws + 56754176);    // over dead raw/gateh
  u16* rgb_bf  = (u16*)(ws + 107085824);
  u16* pose_bf = (u16*)(ws + 132251648);
  u16* flow_bf = (u16*)(ws + 153223168);
  u16* ctxg    = (u16*)(ws + 132251648);   // over dead pose_bf
  u16* fusedb  = (u16*)(ws + 149028864);   // over dead flow_bf
  u16* cls_tmp = (u16*)(ws + 165806080);
  u16* h_bf    = (u16*)(ws + 174194688);

  // ---- 1. convert inputs + GEMM weights to bf16 ----------------------------
  CvtJobs J;
  const float* srcs[10] = {rgb, pose, flow, rgb_w, pose_w, flow_w, in_w, out_w, gw1, cw1};
  u16* dsts[10] = {rgb_bf, pose_bf, flow_bf, w_rgb, w_pose, w_flow, w_in, w_out, w_g1, w_c1};
  int ns[10] = {BATCH * 768, BATCH * 640, BATCH * 1024, 512 * 768, 512 * 640,
                512 * 1024, 1536 * 512, 512 * 512, 512 * 1536, 256 * 512};
  for (int i = 0; i < 10; ++i) { J.s[i] = srcs[i]; J.d[i] = dsts[i]; J.n4[i] = ns[i] / 4; }
  cvt_multi<<<2048, 256, 0, stream>>>(J);

  dim3 wblk(64);
  // ---- 2. 3 proj GEMMs (wave-autonomous) -> raw (B,1536); ln3 -> rpf -------
  gemm_w<1><<<2048, wblk, 0, stream>>>(rgb_bf,  w_rgb,  rgb_b,  raw, 768,  1536, 0,    8);
  gemm_w<1><<<2048, wblk, 0, stream>>>(pose_bf, w_pose, pose_b, raw, 640,  1536, 512,  8);
  gemm_w<1><<<2048, wblk, 0, stream>>>(flow_bf, w_flow, flow_b, raw, 1024, 1536, 1024, 8);
  ln3_k<<<BATCH / 2, dim3(384), 0, stream>>>(raw, rpf, rgb_g, rgb_beta, pose_g, pose_beta, flow_g, flow_beta);

  // ---- 3. gate MLP (needs only rpf): gate1 GEMM + gate2 softmax ------------
  gemm_w<2><<<2048, wblk, 0, stream>>>(rpf, w_g1, gb1, gateh, 1536, 512, 0, 8);
  gate2_k<<<BATCH / 4, dim3(256), 0, stream>>>(gateh, gw2, gb2, gate_out);

  // ---- 4. qkv GEMM + gated attention, 2 chunks of 8192 samples -------------
  for (int c = 0; c < 2; ++c) {
    const u16* a_chunk = rpf + (size_t)c * 8192 * 1536;   // (24576,512) view
    gemm_w<1><<<24 * 384, wblk, 0, stream>>>(a_chunk, w_in, in_b, qkv_buf, 512, 1536, 0, 24);
    attn_gate_k<<<8192 / 4, dim3(256), 0, stream>>>(qkv_buf, gate_out, ctxg, c * 8192);
  }

  // ---- 5. out-proj on the GATED sum (B x 512 -> 512) -----------------------
  gemm_w<1><<<2048, wblk, 0, stream>>>(ctxg, w_out, out_b, fusedb, 512, 512, 0, 8);

  // ---- 6. classifier: GEMM -> LN+ReLU -> logits ----------------------------
  gemm_w<1><<<1024, wblk, 0, stream>>>(fusedb, w_c1, cb1, cls_tmp, 512, 256, 0, 4);
  ln_relu_k<256><<<BATCH / 4, dim3(256), 0, stream>>>(cls_tmp, h_bf, cg, cbeta);
  cls2_k<<<BATCH / 4, dim3(256), 0, stream>>>(h_bf, cw2, cb2, logits_out);

  (void)in_sizes; (void)n_in; (void)out_size; (void)ws_size;
}

// Round 9
// 551.973 us; speedup vs baseline: 1.6365x; 1.1089x over previous
//
#include <hip/hip_runtime.h>

// ---------------------------------------------------------------------------
// AttentionFusion: 3-modality proj(+LN+ReLU) -> 3-token MHA -> gated fusion
// -> classifier.  B=16384, E=512, H=8, HD=64, NC=6.
// R9: revert GEMM core to R6 (best: 550 us; barrier-dbuf + XCD swizzle —
// R7/R8 barrier-free experiments both regressed) and consolidate:
//  - qkv chunk 1 + gate1 merged into one multi-job GEMM launch
//  - gate2 folded into the attention kernel (inline softmax gate per sample)
//  - classifier LN+ReLU+final matmul fused into one cls_tail kernel
// 13 -> 10 launches; h_bf round-trip and gate2 pass eliminated.
// Workspace peak 165,806,080 B (same as R6, ran clean).
// ---------------------------------------------------------------------------

typedef unsigned short u16;
typedef __bf16 bf16x8 __attribute__((ext_vector_type(8)));
typedef float f32x4  __attribute__((ext_vector_type(4)));
typedef unsigned short u16x8 __attribute__((ext_vector_type(8)));
typedef unsigned short u16x4 __attribute__((ext_vector_type(4)));

#define BATCH 16384

__device__ __forceinline__ u16 f2b(float f) {   // RNE f32->bf16
  union { float f; unsigned int u; } c; c.f = f;
  unsigned int u = c.u;
  return (u16)((u + 0x7fffu + ((u >> 16) & 1u)) >> 16);
}
__device__ __forceinline__ float b2f(u16 h) {
  union { unsigned int u; float f; } c; c.u = ((unsigned int)h) << 16;
  return c.f;
}

// ---------------------------------------------------------------------------
// fp32 -> bf16 conversion for the 7 GEMM weight matrices (6.4 MB total)
// ---------------------------------------------------------------------------
struct CvtJobs {
  const float* s[7];
  u16* d[7];
  int n4[7];
};

__global__ __launch_bounds__(256) void cvt_w(CvtJobs J) {
  const int stride = gridDim.x * blockDim.x;
  const int tid = blockIdx.x * blockDim.x + threadIdx.x;
  for (int ji = 0; ji < 7; ++ji) {
    const f32x4* __restrict__ s = (const f32x4*)J.s[ji];
    u16x4* __restrict__ d = (u16x4*)J.d[ji];
    const int n4 = J.n4[ji];
    for (int i = tid; i < n4; i += stride) {
      f32x4 v = s[i];
      u16x4 o;
      #pragma unroll
      for (int c = 0; c < 4; ++c) o[c] = f2b(v[c]);
      d[i] = o;
    }
  }
}

// ---------------------------------------------------------------------------
// bf16 GEMM body (R6-proven): C = A(M,K) @ B(N,K)^T + bias [+relu].
// 128x128 tile, BK=32, 4 waves each 64x64 (4x4 of 16x16x32 MFMA).
// LDS double-buffered, ONE barrier per k-step, prefetch after the barrier.
// ---------------------------------------------------------------------------
__device__ __forceinline__ void gemm_body(
    const u16* __restrict__ A, const u16* __restrict__ Bw,
    const float* __restrict__ bias, u16* __restrict__ C,
    int K, int ldc, int coff, int relu, int m0, int n0,
    u16 (*As)[4096], u16 (*Bs)[4096])
{
  const int t = threadIdx.x;
  const int wave = t >> 6, lane = t & 63;
  const int wm = wave & 1, wn = wave >> 1;
  const int lr  = lane & 15;
  const int lk8 = (lane >> 4) << 3;
  const int srow = t >> 2;
  const int scol = (t & 3) << 4;

  f32x4 acc[4][4] = {};

  const size_t rowB = (size_t)K * 2;
  const char* Ab = (const char*)A + (size_t)m0 * rowB + scol;
  const char* Bb = (const char*)Bw + (size_t)n0 * rowB + scol;

  auto stage = [&](int s, int buf) {
    const char* Ak = Ab + (size_t)s * 64;
    const char* Bk = Bb + (size_t)s * 64;
    #pragma unroll
    for (int j = 0; j < 2; ++j) {
      __builtin_amdgcn_global_load_lds(
          (const __attribute__((address_space(1))) void*)(Ak + (size_t)(j * 64 + srow) * rowB),
          (__attribute__((address_space(3))) void*)((char*)As[buf] + (j << 12) + (wave << 10)),
          16, 0, 0);
      __builtin_amdgcn_global_load_lds(
          (const __attribute__((address_space(1))) void*)(Bk + (size_t)(j * 64 + srow) * rowB),
          (__attribute__((address_space(3))) void*)((char*)Bs[buf] + (j << 12) + (wave << 10)),
          16, 0, 0);
    }
  };

  const int nsteps = K >> 5;
  stage(0, 0);
  for (int s = 0; s < nsteps; ++s) {
    const int cur = s & 1;
    __syncthreads();
    if (s + 1 < nsteps) stage(s + 1, cur ^ 1);

    bf16x8 af[4], bfr[4];
    #pragma unroll
    for (int mi = 0; mi < 4; ++mi) {
      const int r = (wm << 6) + (mi << 4) + lr;
      af[mi] = __builtin_bit_cast(bf16x8, *(const u16x8*)&As[cur][r * 32 + lk8]);
    }
    #pragma unroll
    for (int ni = 0; ni < 4; ++ni) {
      const int r = (wn << 6) + (ni << 4) + lr;
      bfr[ni] = __builtin_bit_cast(bf16x8, *(const u16x8*)&Bs[cur][r * 32 + lk8]);
    }
    #pragma unroll
    for (int mi = 0; mi < 4; ++mi)
      #pragma unroll
      for (int ni = 0; ni < 4; ++ni)
        acc[mi][ni] = __builtin_amdgcn_mfma_f32_16x16x32_bf16(
            af[mi], bfr[ni], acc[mi][ni], 0, 0, 0);
  }

  // C/D layout (m89-verified): col = lane&15, row = (lane>>4)*4 + reg
  const int rquad = (lane >> 4) << 2;
  #pragma unroll
  for (int ni = 0; ni < 4; ++ni) {
    const int col = n0 + (wn << 6) + (ni << 4) + lr;
    const float bv = bias[col];
    #pragma unroll
    for (int mi = 0; mi < 4; ++mi) {
      const int rowb = m0 + (wm << 6) + (mi << 4) + rquad;
      #pragma unroll
      for (int r = 0; r < 4; ++r) {
        float v = acc[mi][ni][r] + bv;
        if (relu) v = fmaxf(v, 0.0f);
        C[(size_t)(rowb + r) * ldc + coff + col] = f2b(v);
      }
    }
  }
}

// Single-job GEMM (XCD-swizzled 1-D grid: NB N-blocks of one M-block differ
// by 8 in linear id -> same XCD under round-robin dispatch).
__global__ __launch_bounds__(256) void gemm128(
    const u16* __restrict__ A, const u16* __restrict__ Bw,
    const float* __restrict__ bias, u16* __restrict__ C,
    int K, int ldc, int coff, int NB, int relu)
{
  __shared__ __align__(16) u16 As[2][4096];
  __shared__ __align__(16) u16 Bs[2][4096];
  const int id = blockIdx.x;
  const int rr = id & 7, jj = id >> 3;
  const int nb = jj % NB;
  const int mb = rr + ((jj / NB) << 3);
  gemm_body(A, Bw, bias, C, K, ldc, coff, relu, mb << 7, nb << 7, As, Bs);
}

// Two-job GEMM: blocks [0,split) run job0, [split,·) job1.  Used to merge
// the qkv chunk-1 GEMM with the independent gate1 GEMM in one launch.
struct GJob {
  const u16* A; const u16* Bw; const float* bias; u16* C;
  int K, ldc, coff, NB, relu;
};
__global__ __launch_bounds__(256) void gemm_mj(GJob j0, GJob j1, int split) {
  __shared__ __align__(16) u16 As[2][4096];
  __shared__ __align__(16) u16 Bs[2][4096];
  GJob j = (blockIdx.x < split) ? j0 : j1;
  const int id = (blockIdx.x < split) ? blockIdx.x : (blockIdx.x - split);
  const int rr = id & 7, jj = id >> 3;
  const int nb = jj % j.NB;
  const int mb = rr + ((jj / j.NB) << 3);
  gemm_body(j.A, j.Bw, j.bias, j.C, j.K, j.ldc, j.coff, j.relu,
            mb << 7, nb << 7, As, Bs);
}

// ---------------------------------------------------------------------------
// LN+ReLU over all 3 modality slices of raw (B,1536) bf16 -> rpf (B,1536).
// 384 threads = 6 waves = 2 samples x 3 modalities; one wave per 512-slice.
// ---------------------------------------------------------------------------
__global__ __launch_bounds__(384) void ln3_k(
    const u16* __restrict__ raw, u16* __restrict__ dst,
    const float* __restrict__ g0, const float* __restrict__ b0,
    const float* __restrict__ g1, const float* __restrict__ b1,
    const float* __restrict__ g2, const float* __restrict__ b2)
{
  const int wave = threadIdx.x >> 6, lane = threadIdx.x & 63;
  const int m = wave % 3;
  const int b = blockIdx.x * 2 + wave / 3;
  const size_t off = (size_t)b * 1536 + m * 512 + lane * 8;
  u16x8 xa = *(const u16x8*)&raw[off];
  float x[8];
  float sum = 0.f, sq = 0.f;
  #pragma unroll
  for (int d = 0; d < 8; ++d) { float f = b2f(xa[d]); x[d] = f; sum += f; sq += f * f; }
  #pragma unroll
  for (int o = 32; o > 0; o >>= 1) { sum += __shfl_xor(sum, o); sq += __shfl_xor(sq, o); }
  const float mean = sum * (1.0f / 512.0f);
  const float var = sq * (1.0f / 512.0f) - mean * mean;
  const float rs = rsqrtf(var + 1e-5f);
  const float* g = (m == 0) ? g0 : (m == 1) ? g1 : g2;
  const float* bb = (m == 0) ? b0 : (m == 1) ? b1 : b2;
  u16x8 o;
  #pragma unroll
  for (int d = 0; d < 8; ++d) {
    float y = (x[d] - mean) * rs * g[lane * 8 + d] + bb[lane * 8 + d];
    o[d] = f2b(fmaxf(y, 0.0f));
  }
  *(u16x8*)&dst[off] = o;
}

// ---------------------------------------------------------------------------
// 3-token 8-head attention + INLINE gate (gate2 softmax folded in) for a
// chunk of samples.  qkv: (3*NB,1536) bf16 [q|k|v].  For each sample b the
// 64-lane wave first computes gate = softmax(gateh[b]·gw2^T + gb2) (shuffle
// reduce), writes gate_out, then emits the GATED context sum directly:
// ctxg[b0+b] = sum_i gate_i * ctx_i  (exact: out-proj linear, sum g = 1).
// ---------------------------------------------------------------------------
__global__ __launch_bounds__(256) void attn_gate_k(
    const u16* __restrict__ qkv, const u16* __restrict__ gateh,
    const float* __restrict__ gw2, const float* __restrict__ gb2,
    float* __restrict__ gate_out, u16* __restrict__ ctxg, int b0)
{
  const int wave = threadIdx.x >> 6;
  const int lane = threadIdx.x & 63;
  const int b = blockIdx.x * 4 + wave;          // chunk-local sample
  const int h = (lane >> 3) & 7;
  const int ld = lane & 7;

  // ---- inline gate2: s_j = gateh[b] . gw2[j] + gb2[j]; softmax ------------
  float gx[8];
  u16x8 ga = *(const u16x8*)&gateh[(size_t)(b0 + b) * 512 + lane * 8];
  #pragma unroll
  for (int d = 0; d < 8; ++d) gx[d] = b2f(ga[d]);
  float s3[3] = {0.f, 0.f, 0.f};
  #pragma unroll
  for (int j = 0; j < 3; ++j) {
    const float* w = gw2 + j * 512 + lane * 8;
    #pragma unroll
    for (int d = 0; d < 8; ++d) s3[j] += gx[d] * w[d];
  }
  #pragma unroll
  for (int m = 1; m < 64; m <<= 1)
    #pragma unroll
    for (int j = 0; j < 3; ++j) s3[j] += __shfl_xor(s3[j], m);
  #pragma unroll
  for (int j = 0; j < 3; ++j) s3[j] += gb2[j];
  const float gmx = fmaxf(s3[0], fmaxf(s3[1], s3[2]));
  float g0 = __expf(s3[0] - gmx), g1 = __expf(s3[1] - gmx), g2 = __expf(s3[2] - gmx);
  const float ginv = 1.0f / (g0 + g1 + g2);
  g0 *= ginv; g1 *= ginv; g2 *= ginv;
  if (lane == 0) {
    gate_out[(size_t)(b0 + b) * 3 + 0] = g0;
    gate_out[(size_t)(b0 + b) * 3 + 1] = g1;
    gate_out[(size_t)(b0 + b) * 3 + 2] = g2;
  }
  const float gg[3] = {g0, g1, g2};

  // ---- attention ----------------------------------------------------------
  const size_t rb = (size_t)(3 * b) * 1536 + h * 64 + ld * 8;
  float q[3][8], k[3][8], v[3][8];
  #pragma unroll
  for (int i = 0; i < 3; ++i) {
    u16x8 qa = *(const u16x8*)&qkv[rb + (size_t)i * 1536];
    u16x8 ka = *(const u16x8*)&qkv[rb + (size_t)i * 1536 + 512];
    u16x8 va = *(const u16x8*)&qkv[rb + (size_t)i * 1536 + 1024];
    #pragma unroll
    for (int d = 0; d < 8; ++d) { q[i][d] = b2f(qa[d]); k[i][d] = b2f(ka[d]); v[i][d] = b2f(va[d]); }
  }
  float s[9];
  #pragma unroll
  for (int i = 0; i < 3; ++i)
    #pragma unroll
    for (int j = 0; j < 3; ++j) {
      float a = 0.f;
      #pragma unroll
      for (int d = 0; d < 8; ++d) a += q[i][d] * k[j][d];
      s[i * 3 + j] = a;
    }
  #pragma unroll
  for (int m = 1; m < 8; m <<= 1)
    #pragma unroll
    for (int e = 0; e < 9; ++e) s[e] += __shfl_xor(s[e], m);

  float o[8] = {};
  const float sc = 0.125f;  // 1/sqrt(64)
  #pragma unroll
  for (int i = 0; i < 3; ++i) {
    const float a0 = s[i * 3 + 0] * sc, a1 = s[i * 3 + 1] * sc, a2 = s[i * 3 + 2] * sc;
    const float mx = fmaxf(a0, fmaxf(a1, a2));
    float e0 = __expf(a0 - mx), e1 = __expf(a1 - mx), e2 = __expf(a2 - mx);
    const float inv = gg[i] / (e0 + e1 + e2);
    e0 *= inv; e1 *= inv; e2 *= inv;
    #pragma unroll
    for (int d = 0; d < 8; ++d)
      o[d] += e0 * v[0][d] + e1 * v[1][d] + e2 * v[2][d];
  }
  u16x8 ov;
  #pragma unroll
  for (int d = 0; d < 8; ++d) ov[d] = f2b(o[d]);
  *(u16x8*)&ctxg[(size_t)(b0 + b) * 512 + h * 64 + ld * 8] = ov;
}

// ---------------------------------------------------------------------------
// classifier tail: LN(256)+ReLU then logits = h @ cw2(6,256)^T + cb2.
// One wave per sample (4 samples / 256-thread block); no h round-trip.
// ---------------------------------------------------------------------------
__global__ __launch_bounds__(256) void cls_tail_k(
    const u16* __restrict__ cls_tmp, const float* __restrict__ cg,
    const float* __restrict__ cbeta, const float* __restrict__ cw2,
    const float* __restrict__ cb2, float* __restrict__ logits)
{
  const int wave = threadIdx.x >> 6, lane = threadIdx.x & 63;
  const int b = blockIdx.x * 4 + wave;
  float x[4];
  u16x4 xa = *(const u16x4*)&cls_tmp[(size_t)b * 256 + lane * 4];
  float sum = 0.f, sq = 0.f;
  #pragma unroll
  for (int d = 0; d < 4; ++d) { float f = b2f(xa[d]); x[d] = f; sum += f; sq += f * f; }
  #pragma unroll
  for (int m = 32; m > 0; m >>= 1) { sum += __shfl_xor(sum, m); sq += __shfl_xor(sq, m); }
  const float mean = sum * (1.0f / 256.0f);
  const float var = sq * (1.0f / 256.0f) - mean * mean;
  const float rs = rsqrtf(var + 1e-5f);
  float h[4];
  #pragma unroll
  for (int d = 0; d < 4; ++d) {
    const int c = lane * 4 + d;
    h[d] = fmaxf((x[d] - mean) * rs * cg[c] + cbeta[c], 0.0f);
  }
  float s[6] = {};
  #pragma unroll
  for (int j = 0; j < 6; ++j) {
    const float* w = cw2 + j * 256 + lane * 4;
    #pragma unroll
    for (int d = 0; d < 4; ++d) s[j] += h[d] * w[d];
  }
  #pragma unroll
  for (int m = 1; m < 64; m <<= 1)
    #pragma unroll
    for (int j = 0; j < 6; ++j) s[j] += __shfl_xor(s[j], m);
  if (lane < 6) logits[(size_t)b * 6 + lane] = s[lane] + cb2[lane];
}

// ---------------------------------------------------------------------------
// Fused 3-modality projection GEMM (R6 version): fp32 A read directly, in-
// register bf16 cvt + LDS dbuf, one barrier/step, XCD-swizzled grid of 1536.
// ---------------------------------------------------------------------------
struct P3 {
  const float* A[3];
  const u16* W[3];
  const float* bias[3];
  int K[3];
  int coff[3];
  u16* C;
};

__global__ __launch_bounds__(256) void proj3_k(P3 p) {
  __shared__ __align__(16) u16 As[2][4096];
  __shared__ __align__(16) u16 Bs[2][4096];
  const int id = blockIdx.x;
  const int rr = id & 7, jj = id >> 3;
  const int nb = jj & 3;
  const int mz = rr + ((jj >> 2) << 3);
  const int mb = mz & 127;
  const int z  = mz >> 7;
  const int m0 = mb << 7, n0 = nb << 7;

  const float* __restrict__ A = p.A[z];
  const u16* __restrict__ Bw = p.W[z];
  const int K = p.K[z];

  const int t = threadIdx.x;
  const int wave = t >> 6, lane = t & 63;
  const int wm = wave & 1, wn = wave >> 1;
  const int lr  = lane & 15;
  const int lk8 = (lane >> 4) << 3;
  const int ar = t >> 3;
  const int ac = (t & 7) << 2;
  const int srow = t >> 2;
  const int scol = (t & 3) << 4;

  f32x4 acc[4][4] = {};

  const size_t rowA = (size_t)K;
  const size_t rowB = (size_t)K * 2;
  const float* Abase = A + (size_t)m0 * rowA + ac;
  const char* Bb = (const char*)Bw + (size_t)n0 * rowB + scol;

  f32x4 areg[4];
  auto loadA = [&](int s) {
    const float* Ak = Abase + s * 32;
    #pragma unroll
    for (int j = 0; j < 4; ++j)
      areg[j] = *(const f32x4*)(Ak + (size_t)(j * 32 + ar) * rowA);
  };
  auto writeA = [&](int buf) {
    #pragma unroll
    for (int j = 0; j < 4; ++j) {
      u16x4 o;
      #pragma unroll
      for (int c = 0; c < 4; ++c) o[c] = f2b(areg[j][c]);
      *(u16x4*)&As[buf][(j * 32 + ar) * 32 + ac] = o;
    }
  };
  auto stageB = [&](int s, int buf) {
    const char* Bk = Bb + (size_t)s * 64;
    #pragma unroll
    for (int j = 0; j < 2; ++j)
      __builtin_amdgcn_global_load_lds(
          (const __attribute__((address_space(1))) void*)(Bk + (size_t)(j * 64 + srow) * rowB),
          (__attribute__((address_space(3))) void*)((char*)Bs[buf] + (j << 12) + (wave << 10)),
          16, 0, 0);
  };

  const int nsteps = K >> 5;
  loadA(0);
  stageB(0, 0);
  writeA(0);
  for (int s = 0; s < nsteps; ++s) {
    const int cur = s & 1;
    __syncthreads();
    if (s + 1 < nsteps) { loadA(s + 1); stageB(s + 1, cur ^ 1); }

    bf16x8 af[4], bfr[4];
    #pragma unroll
    for (int mi = 0; mi < 4; ++mi) {
      const int r = (wm << 6) + (mi << 4) + lr;
      af[mi] = __builtin_bit_cast(bf16x8, *(const u16x8*)&As[cur][r * 32 + lk8]);
    }
    #pragma unroll
    for (int ni = 0; ni < 4; ++ni) {
      const int r = (wn << 6) + (ni << 4) + lr;
      bfr[ni] = __builtin_bit_cast(bf16x8, *(const u16x8*)&Bs[cur][r * 32 + lk8]);
    }
    #pragma unroll
    for (int mi = 0; mi < 4; ++mi)
      #pragma unroll
      for (int ni = 0; ni < 4; ++ni)
        acc[mi][ni] = __builtin_amdgcn_mfma_f32_16x16x32_bf16(
            af[mi], bfr[ni], acc[mi][ni], 0, 0, 0);

    if (s + 1 < nsteps) writeA(cur ^ 1);
  }

  const int rquad = (lane >> 4) << 2;
  #pragma unroll
  for (int ni = 0; ni < 4; ++ni) {
    const int col = n0 + (wn << 6) + (ni << 4) + lr;
    const float bv = p.bias[z][col];
    #pragma unroll
    for (int mi = 0; mi < 4; ++mi) {
      const int rowb = m0 + (wm << 6) + (mi << 4) + rquad;
      #pragma unroll
      for (int r = 0; r < 4; ++r) {
        p.C[(size_t)(rowb + r) * 1536 + p.coff[z] + col] = f2b(acc[mi][ni][r] + bv);
      }
    }
  }
}

// ---------------------------------------------------------------------------
extern "C" void kernel_launch(void* const* d_in, const int* in_sizes, int n_in,
                              void* d_out, int out_size, void* d_ws, size_t ws_size,
                              hipStream_t stream) {
  const float* rgb       = (const float*)d_in[0];
  const float* pose      = (const float*)d_in[1];
  const float* flow      = (const float*)d_in[2];
  const float* rgb_w     = (const float*)d_in[3];
  const float* rgb_b     = (const float*)d_in[4];
  const float* rgb_g     = (const float*)d_in[5];
  const float* rgb_beta  = (const float*)d_in[6];
  const float* pose_w    = (const float*)d_in[7];
  const float* pose_b    = (const float*)d_in[8];
  const float* pose_g    = (const float*)d_in[9];
  const float* pose_beta = (const float*)d_in[10];
  const float* flow_w    = (const float*)d_in[11];
  const float* flow_b    = (const float*)d_in[12];
  const float* flow_g    = (const float*)d_in[13];
  const float* flow_beta = (const float*)d_in[14];
  const float* in_w      = (const float*)d_in[15];
  const float* in_b      = (const float*)d_in[16];
  const float* out_w     = (const float*)d_in[17];
  const float* out_b     = (const float*)d_in[18];
  const float* gw1       = (const float*)d_in[19];
  const float* gb1       = (const float*)d_in[20];
  const float* gw2       = (const float*)d_in[21];
  const float* gb2       = (const float*)d_in[22];
  const float* cw1       = (const float*)d_in[23];
  const float* cb1       = (const float*)d_in[24];
  const float* cg        = (const float*)d_in[25];
  const float* cbeta     = (const float*)d_in[26];
  const float* cw2       = (const float*)d_in[27];
  const float* cb2       = (const float*)d_in[28];

  float* logits_out = (float*)d_out;                      // (16384, 6)
  float* gate_out   = (float*)d_out + (size_t)BATCH * 6;  // (16384, 3)

  // ---- static workspace layout, peak 165,806,080 B (= R6, ran clean) -------
  char* ws = (char*)d_ws;
  u16* w_rgb  = (u16*)(ws + 0);
  u16* w_pose = (u16*)(ws + 786432);
  u16* w_flow = (u16*)(ws + 1441792);
  u16* w_in   = (u16*)(ws + 2490368);
  u16* w_out  = (u16*)(ws + 4063232);
  u16* w_g1   = (u16*)(ws + 4587520);
  u16* w_c1   = (u16*)(ws + 6160384);
  u16* rpf     = (u16*)(ws + 6422528);     // (B,1536) bf16 — also (3B,512) view
  u16* raw     = (u16*)(ws + 56754176);    // (B,1536) pre-LN
  u16* qkv_buf = (u16*)(ws + 56754176);    // (24576,1536) chunk (raw dead)
  u16* gateh   = (u16*)(ws + 132251648);   // (B,512)
  u16* fusedb  = (u16*)(ws + 132251648);   // overlay (gateh dead after attn2)
  u16* ctxg    = (u16*)(ws + 149028864);   // (B,512)
  u16* cls_tmp = (u16*)(ws + 149028864);   // (B,256) overlay (ctxg dead)

  // ---- 1. convert GEMM weights to bf16 (6.4 MB) ----------------------------
  CvtJobs J;
  const float* srcs[7] = {rgb_w, pose_w, flow_w, in_w, out_w, gw1, cw1};
  u16* dsts[7] = {w_rgb, w_pose, w_flow, w_in, w_out, w_g1, w_c1};
  int ns[7] = {512 * 768, 512 * 640, 512 * 1024, 1536 * 512, 512 * 512, 512 * 1536, 256 * 512};
  for (int i = 0; i < 7; ++i) { J.s[i] = srcs[i]; J.d[i] = dsts[i]; J.n4[i] = ns[i] / 4; }
  cvt_w<<<128, 256, 0, stream>>>(J);

  dim3 blk(256);
  // ---- 2. fused 3-proj GEMM (fp32 A direct) -> raw; ln3 -> rpf -------------
  P3 p;
  p.A[0] = rgb;  p.W[0] = w_rgb;  p.bias[0] = rgb_b;  p.K[0] = 768;  p.coff[0] = 0;
  p.A[1] = pose; p.W[1] = w_pose; p.bias[1] = pose_b; p.K[1] = 640;  p.coff[1] = 512;
  p.A[2] = flow; p.W[2] = w_flow; p.bias[2] = flow_b; p.K[2] = 1024; p.coff[2] = 1024;
  p.C = raw;
  proj3_k<<<1536, blk, 0, stream>>>(p);
  ln3_k<<<BATCH / 2, dim3(384), 0, stream>>>(raw, rpf, rgb_g, rgb_beta, pose_g, pose_beta, flow_g, flow_beta);

  // ---- 3. merged launch: qkv chunk-1 GEMM (2304 blocks) + gate1 (512) ------
  GJob jq, jg;
  jq.A = rpf;                 jq.Bw = w_in; jq.bias = in_b; jq.C = qkv_buf;
  jq.K = 512;  jq.ldc = 1536; jq.coff = 0; jq.NB = 12; jq.relu = 0;
  jg.A = rpf;                 jg.Bw = w_g1; jg.bias = gb1; jg.C = gateh;
  jg.K = 1536; jg.ldc = 512;  jg.coff = 0; jg.NB = 4;  jg.relu = 1;
  gemm_mj<<<2304 + 512, blk, 0, stream>>>(jq, jg, 2304);

  // ---- 4. attention+gate chunk 1 -------------------------------------------
  attn_gate_k<<<8192 / 4, blk, 0, stream>>>(qkv_buf, gateh, gw2, gb2, gate_out, ctxg, 0);

  // ---- 5. qkv chunk-2 GEMM + attention+gate chunk 2 ------------------------
  gemm128<<<2304, blk, 0, stream>>>(rpf + (size_t)8192 * 1536, w_in, in_b, qkv_buf,
                                    512, 1536, 0, 12, 0);
  attn_gate_k<<<8192 / 4, blk, 0, stream>>>(qkv_buf, gateh, gw2, gb2, gate_out, ctxg, 8192);

  // ---- 6. out-proj on the GATED sum (B x 512 -> 512) -----------------------
  gemm128<<<512, blk, 0, stream>>>(ctxg, w_out, out_b, fusedb, 512, 512, 0, 4, 0);

  // ---- 7. classifier: GEMM -> fused LN+ReLU+logits -------------------------
  gemm128<<<256, blk, 0, stream>>>(fusedb, w_c1, cb1, cls_tmp, 512, 256, 0, 2, 0);
  cls_tail_k<<<BATCH / 4, blk, 0, stream>>>(cls_tmp, cg, cbeta, cw2, cb2, logits_out);

  (void)in_sizes; (void)n_in; (void)out_size; (void)ws_size;
}